// Round 5
// baseline (167.392 us; speedup 1.0000x reference)
//
#include <hip/hip_runtime.h>
#include <hip/hip_fp16.h>

#define ALPHA 0.3f
#define B_SZ 4096
#define D_SZ 1024
#define CT_STRIDE 132   // multiple of 4 (aligned half4 stores), 2-per-bank-ish scans
#define BIGF 3.0e38f

typedef __attribute__((ext_vector_type(8))) _Float16 half8;
typedef __attribute__((ext_vector_type(4))) _Float16 half4;
typedef __attribute__((ext_vector_type(4))) float floatx4;

typedef __attribute__((address_space(1))) const void* gas_t;
typedef __attribute__((address_space(3))) void* las_t;

__device__ __forceinline__ float wave_reduce_add(float v) {
#pragma unroll
    for (int off = 32; off; off >>= 1) v += __shfl_xor(v, off);
    return v;
}

// sorted ascending insert of x into best[0..9] (branchless)
__device__ __forceinline__ void insert10(float (&best)[10], float x) {
#pragma unroll
    for (int p = 0; p < 10; ++p) {
        float lo = fminf(best[p], x);
        x = fmaxf(best[p], x);
        best[p] = lo;
    }
}

__device__ __forceinline__ unsigned short h16(float x) {
    return __builtin_bit_cast(unsigned short, (_Float16)x);
}

// ---------------------------------------------------------------------------
// prep: fp32 -> fp16 convert of both inputs, row norms x2/y2, and the exact
// per-anchor threshold m[i] = ||x_i - y_i|| + alpha (computed in fp32).
// ---------------------------------------------------------------------------
__global__ void __launch_bounds__(256) prep_kernel(
    const float* __restrict__ in1, const float* __restrict__ in2,
    _Float16* __restrict__ Xh, _Float16* __restrict__ Yh,
    float* __restrict__ x2, float* __restrict__ y2, float* __restrict__ mth) {
    int row = blockIdx.x;
    int t = threadIdx.x;
    const float4* a4 = (const float4*)(in1 + (size_t)row * D_SZ);
    const float4* b4 = (const float4*)(in2 + (size_t)row * D_SZ);
    float4 a = a4[t], b = b4[t];
    half4 ha = {(_Float16)a.x, (_Float16)a.y, (_Float16)a.z, (_Float16)a.w};
    half4 hb = {(_Float16)b.x, (_Float16)b.y, (_Float16)b.z, (_Float16)b.w};
    ((half4*)(Xh + (size_t)row * D_SZ))[t] = ha;
    ((half4*)(Yh + (size_t)row * D_SZ))[t] = hb;
    float sa = a.x * a.x + a.y * a.y + a.z * a.z + a.w * a.w;
    float sb = b.x * b.x + b.y * b.y + b.z * b.z + b.w * b.w;
    float d0 = a.x - b.x, d1 = a.y - b.y, d2v = a.z - b.z, d3 = a.w - b.w;
    float sd = d0 * d0 + d1 * d1 + d2v * d2v + d3 * d3;
    sa = wave_reduce_add(sa);
    sb = wave_reduce_add(sb);
    sd = wave_reduce_add(sd);
    __shared__ float red[3][4];
    int wave = t >> 6, lane = t & 63;
    if (lane == 0) { red[0][wave] = sa; red[1][wave] = sb; red[2][wave] = sd; }
    __syncthreads();
    if (t == 0) {
        x2[row] = red[0][0] + red[0][1] + red[0][2] + red[0][3];
        y2[row] = red[1][0] + red[1][1] + red[1][2] + red[1][3];
        mth[row] = sqrtf(red[2][0] + red[2][1] + red[2][2] + red[2][3]) + ALPHA;
    }
}

// ---------------------------------------------------------------------------
// gemm_topk: G = Xh @ Yh^T tile (128x128), BK=64 (16 K-iters, half the
// barriers of BK=32), XOR k-slice swizzle (LDS slot (r,s') holds global slice
// s'^(r&7)), global_load_lds 16B. Fused epilogue: d2 tile -> LDS fp16
// TRANSPOSED (Ct[col*132+row], aligned half4 writes), per-row / per-col
// top-10, in-wave half-pair merge, fp16 candidates (10 per (row,tile)).
// ---------------------------------------------------------------------------
__global__ void __launch_bounds__(256, 4) gemm_topk_kernel(
    const _Float16* __restrict__ Xh, const _Float16* __restrict__ Yh,
    const float* __restrict__ x2, const float* __restrict__ y2,
    _Float16* __restrict__ CandI, _Float16* __restrict__ CandR) {
    __shared__ _Float16 smem[16896];   // 33792 B: As+Bs (16384 h) | Ct (16892 h)
    _Float16* As = smem;               // 128 x 64 halves
    _Float16* Bs = smem + 8192;
    int tid = threadIdx.x;
    int wave = tid >> 6, lane = tid & 63;
    int waveR = wave >> 1, waveC = wave & 1;
    int bx = blockIdx.x, by = blockIdx.y;
    int q = lane >> 4, mrow = lane & 15;

    floatx4 acc[4][4] = {};

    // Staging: 1024 16B-chunks per tile; instr i covers chunks [i*256+wave*64, +64).
    // Chunk c -> LDS slot (r = c>>3, s' = c&7); source slice = s' ^ (r&7).
    const _Float16* gA[4];
    _Float16* la[4];
#pragma unroll
    for (int i = 0; i < 4; ++i) {
        int c = i * 256 + tid;
        int r = c >> 3, sp = c & 7;
        gA[i] = Xh + (size_t)(by * 128 + r) * D_SZ + (sp ^ (r & 7)) * 8;
        la[i] = &As[(i * 256 + wave * 64) * 8];
    }
    const ptrdiff_t bdelta = (Yh + (size_t)bx * 128 * D_SZ) - (Xh + (size_t)by * 128 * D_SZ);

    // Reader offsets (halves): row R, k-slice s = ks*4+q stored at s^(R&7).
    int aoff[2][4];
#pragma unroll
    for (int mi = 0; mi < 4; ++mi) {
        int R = waveR * 64 + mi * 16 + mrow;
        int Rx = R & 7;
        aoff[0][mi] = R * 64 + (q ^ Rx) * 8;
        aoff[1][mi] = R * 64 + ((q + 4) ^ Rx) * 8;
    }
    const int bdel = (waveC - waveR) * 64 * 64;  // boff = aoff + bdel (uniform)

    for (int k0 = 0; k0 < D_SZ; k0 += 64) {
        __syncthreads();
#pragma unroll
        for (int i = 0; i < 4; ++i) {
            __builtin_amdgcn_global_load_lds((gas_t)(const void*)(gA[i] + k0), (las_t)(void*)la[i], 16, 0, 0);
            __builtin_amdgcn_global_load_lds((gas_t)(const void*)(gA[i] + bdelta + k0), (las_t)(void*)(la[i] + 8192), 16, 0, 0);
        }
        __syncthreads();
#pragma unroll
        for (int ks = 0; ks < 2; ++ks) {
            half8 af[4], bf[4];
#pragma unroll
            for (int mi = 0; mi < 4; ++mi) af[mi] = *(const half8*)&As[aoff[ks][mi]];
#pragma unroll
            for (int ni = 0; ni < 4; ++ni) bf[ni] = *(const half8*)&Bs[aoff[ks][ni] + bdel];
#pragma unroll
            for (int mi = 0; mi < 4; ++mi)
#pragma unroll
                for (int ni = 0; ni < 4; ++ni)
                    acc[mi][ni] = __builtin_amdgcn_mfma_f32_16x16x32_f16(af[mi], bf[ni], acc[mi][ni], 0, 0, 0);
        }
    }
    __syncthreads();  // staging LDS dead; Ct takes over

    // Phase 1: d2 tile -> LDS fp16 transposed: Ct[col*132 + row].
    // C/D layout: col = lane&15, row = q*4 + reg -> 4 consecutive rows = half4.
    _Float16* Ct = smem;
#pragma unroll
    for (int ni = 0; ni < 4; ++ni) {
        int lc = waveC * 64 + ni * 16 + mrow;
        float y2v = y2[bx * 128 + lc];
#pragma unroll
        for (int mi = 0; mi < 4; ++mi) {
            int lr0 = waveR * 64 + mi * 16 + q * 4;
            int gr0 = by * 128 + lr0;
            floatx4 v = acc[mi][ni];
            half4 hv = {(_Float16)(x2[gr0 + 0] + y2v - 2.0f * v[0]),
                        (_Float16)(x2[gr0 + 1] + y2v - 2.0f * v[1]),
                        (_Float16)(x2[gr0 + 2] + y2v - 2.0f * v[2]),
                        (_Float16)(x2[gr0 + 3] + y2v - 2.0f * v[3])};
            *(half4*)&Ct[lc * CT_STRIDE + lr0] = hv;
        }
    }
    __syncthreads();

    // Phase 2 (IRR): lanes L and L^32 handle row wave*32+(L&31), one col-half
    // each; merge the two sorted-10 in-wave; lane<32 stores 10 fp16 cands.
    {
        int rloc = wave * 32 + (lane & 31);
        int chalf = lane >> 5;
        int grow = by * 128 + rloc;
        int diagc = grow - bx * 128;
        float best[10];
#pragma unroll
        for (int i = 0; i < 10; ++i) best[i] = BIGF;
#pragma unroll 8
        for (int i = 0; i < 64; ++i) {
            int lc = chalf * 64 + i;
            float x = (float)Ct[lc * CT_STRIDE + rloc];
            if (lc == diagc) x = BIGF;
            insert10(best, x);
        }
        float tmp[10];
#pragma unroll
        for (int k = 0; k < 10; ++k) tmp[k] = __shfl_xor(best[k], 32);
#pragma unroll
        for (int k = 0; k < 10; ++k) insert10(best, tmp[k]);
        if (lane < 32) {
            unsigned int* dst = (unsigned int*)CandI + ((size_t)grow * 32 + bx) * 5;
#pragma unroll
            for (int k = 0; k < 5; ++k)
                dst[k] = (unsigned int)h16(best[2 * k]) | ((unsigned int)h16(best[2 * k + 1]) << 16);
        }
    }

    // Phase 3 (RII): same for columns.
    {
        int cloc = wave * 32 + (lane & 31);
        int rhalf = lane >> 5;
        int gcol = bx * 128 + cloc;
        int diagr = gcol - by * 128;
        float best[10];
#pragma unroll
        for (int i = 0; i < 10; ++i) best[i] = BIGF;
#pragma unroll 8
        for (int i = 0; i < 64; ++i) {
            int lr = rhalf * 64 + i;
            float x = (float)Ct[cloc * CT_STRIDE + lr];
            if (lr == diagr) x = BIGF;
            insert10(best, x);
        }
        float tmp[10];
#pragma unroll
        for (int k = 0; k < 10; ++k) tmp[k] = __shfl_xor(best[k], 32);
#pragma unroll
        for (int k = 0; k < 10; ++k) insert10(best, tmp[k]);
        if (lane < 32) {
            unsigned int* dst = (unsigned int*)CandR + ((size_t)gcol * 32 + by) * 5;
#pragma unroll
            for (int k = 0; k < 5; ++k)
                dst[k] = (unsigned int)h16(best[2 * k]) | ((unsigned int)h16(best[2 * k + 1]) << 16);
        }
    }
}

// ---------------------------------------------------------------------------
// merge: one wave per logical row r in [0, 8192). Reads 320 fp16 candidates
// (32 tiles x 10), selects global 10 smallest, computes s,z.
// ---------------------------------------------------------------------------
__global__ void __launch_bounds__(256) merge_kernel(
    const _Float16* __restrict__ CandI, const _Float16* __restrict__ CandR,
    const float* __restrict__ mth,
    float* __restrict__ Srow, float* __restrict__ Zrow) {
    int wave = threadIdx.x >> 6, lane = threadIdx.x & 63;
    int r = blockIdx.x * 4 + wave;              // 0..8191
    int row = r & (B_SZ - 1);
    const _Float16* cp = ((r < B_SZ) ? CandI : CandR) + (size_t)row * 320;
    float best[10];
#pragma unroll
    for (int i = 0; i < 10; ++i) best[i] = BIGF;
#pragma unroll
    for (int j = 0; j < 5; ++j) insert10(best, (float)cp[j * 64 + lane]);

    float mrow = mth[row];
    float s = 0.f, z = 0.f;
#pragma unroll
    for (int round = 0; round < 10; ++round) {
        float v0 = best[0];
        float g = v0;
#pragma unroll
        for (int off = 32; off; off >>= 1) g = fminf(g, __shfl_xor(g, off));
        unsigned long long ball = __ballot(v0 == g);
        int leader = __ffsll(ball) - 1;
        if (lane == leader) {
#pragma unroll
            for (int p = 0; p < 9; ++p) best[p] = best[p + 1];
            best[9] = BIGF;
        }
        float d = sqrtf(fmaxf(g, 0.f));
        float c = fmaxf(mrow - d, 0.f);
        s += c;
        z += (c == 0.f) ? 1.f : 0.f;
    }
    if (lane == 0) { Srow[r] = s; Zrow[r] = z; }
}

// ---------------------------------------------------------------------------
// finalize: reduce per-row partials -> [loss_irr, loss_rii, bad_irr, bad_rii]
// ---------------------------------------------------------------------------
__global__ void __launch_bounds__(256) finalize_kernel(
    const float* __restrict__ Srow, const float* __restrict__ Zrow,
    float* __restrict__ out) {
    __shared__ float red[256][4];
    int t = threadIdx.x;
    float s0 = 0, s1 = 0, z0 = 0, z1 = 0;
#pragma unroll
    for (int k = 0; k < 8; ++k) {
        int i = k * 256 + t;
        float4 sv = ((const float4*)Srow)[i];
        float4 zv = ((const float4*)Zrow)[i];
        float ss = sv.x + sv.y + sv.z + sv.w;
        float zz = zv.x + zv.y + zv.z + zv.w;
        if (i < 1024) { s0 += ss; z0 += zz; } else { s1 += ss; z1 += zz; }
    }
    red[t][0] = s0; red[t][1] = s1; red[t][2] = z0; red[t][3] = z1;
    __syncthreads();
    for (int off = 128; off > 0; off >>= 1) {
        if (t < off) {
#pragma unroll
            for (int j = 0; j < 4; ++j) red[t][j] += red[t + off][j];
        }
        __syncthreads();
    }
    if (t == 0) {
        const float inv = 1.0f / (float)(B_SZ * 10);
        out[0] = red[0][0] * inv;  // loss_irr
        out[1] = red[0][1] * inv;  // loss_rii
        out[2] = red[0][2] * inv;  // bad_irr
        out[3] = red[0][3] * inv;  // bad_rii
    }
}

// ---------------------------------------------------------------------------
extern "C" void kernel_launch(void* const* d_in, const int* in_sizes, int n_in,
                              void* d_out, int out_size, void* d_ws, size_t ws_size,
                              hipStream_t stream) {
    const float* in1 = (const float*)d_in[0];
    const float* in2 = (const float*)d_in[1];
    float* out = (float*)d_out;

    char* ws = (char*)d_ws;
    const size_t MB = 1024 * 1024;
    _Float16* Xh = (_Float16*)(ws);                  // 8 MiB
    _Float16* Yh = (_Float16*)(ws + 8 * MB);         // 8 MiB
    _Float16* CandI = (_Float16*)(ws + 16 * MB);     // 4096*32*10*2B = 2.62 MB
    _Float16* CandR = (_Float16*)(ws + 19 * MB);     // 2.62 MB
    float* x2   = (float*)(ws + 22 * MB);
    float* y2   = x2 + B_SZ;
    float* mth  = y2 + B_SZ;
    float* Srow = mth + B_SZ;                        // 2*B rows (irr then rii)
    float* Zrow = Srow + 2 * B_SZ;
    const size_t needed = 22 * MB + (size_t)(3 * B_SZ + 4 * B_SZ) * sizeof(float);
    if (ws_size < needed) return;

    hipLaunchKernelGGL(prep_kernel, dim3(B_SZ), dim3(256), 0, stream,
                       in1, in2, Xh, Yh, x2, y2, mth);
    hipLaunchKernelGGL(gemm_topk_kernel, dim3(32, 32), dim3(256), 0, stream,
                       Xh, Yh, x2, y2, CandI, CandR);
    hipLaunchKernelGGL(merge_kernel, dim3(2048), dim3(256), 0, stream,
                       CandI, CandR, mth, Srow, Zrow);
    hipLaunchKernelGGL(finalize_kernel, dim3(1), dim3(256), 0, stream,
                       Srow, Zrow, out);
}

// Round 7
// 146.980 us; speedup vs baseline: 1.1389x; 1.1389x over previous
//
#include <hip/hip_runtime.h>
#include <hip/hip_fp16.h>

#define ALPHA 0.3f
#define B_SZ 4096
#define D_SZ 1024
#define CT_STRIDE 132   // multiple of 4: aligned half4 stores, 2-way banks on scans
#define BIGF 3.0e38f
#define SENT_F 60000.0f // fp16-representable sentinel >> any d2 (~4100 max)

typedef __attribute__((ext_vector_type(8))) _Float16 half8;
typedef __attribute__((ext_vector_type(4))) _Float16 half4;
typedef __attribute__((ext_vector_type(2))) _Float16 half2v;
typedef __attribute__((ext_vector_type(4))) float floatx4;

typedef __attribute__((address_space(1))) const void* gas_t;
typedef __attribute__((address_space(3))) void* las_t;

__device__ __forceinline__ float wave_reduce_add(float v) {
#pragma unroll
    for (int off = 32; off; off >>= 1) v += __shfl_xor(v, off);
    return v;
}

// sorted ascending insert of x into best[0..9] (branchless, scalar f32)
__device__ __forceinline__ void insert10(float (&best)[10], float x) {
#pragma unroll
    for (int p = 0; p < 10; ++p) {
        float lo = fminf(best[p], x);
        x = fmaxf(best[p], x);
        best[p] = lo;
    }
}

// packed: two independent sorted-10 lists (lane0 halves, lane1 halves)
// lowers to v_pk_min_f16 / v_pk_max_f16
__device__ __forceinline__ void insert10p(half2v (&b)[10], half2v x) {
#pragma unroll
    for (int p = 0; p < 10; ++p) {
        half2v lo = __builtin_elementwise_min(b[p], x);
        x = __builtin_elementwise_max(b[p], x);
        b[p] = lo;
    }
}

__device__ __forceinline__ unsigned short h16(float x) {
    return __builtin_bit_cast(unsigned short, (_Float16)x);
}

// ---------------------------------------------------------------------------
// prep: fp32 -> fp16 convert of both inputs, row norms x2/y2, and the exact
// per-anchor threshold m[i] = ||x_i - y_i|| + alpha (computed in fp32).
// ---------------------------------------------------------------------------
__global__ void __launch_bounds__(256) prep_kernel(
    const float* __restrict__ in1, const float* __restrict__ in2,
    _Float16* __restrict__ Xh, _Float16* __restrict__ Yh,
    float* __restrict__ x2, float* __restrict__ y2, float* __restrict__ mth) {
    int row = blockIdx.x;
    int t = threadIdx.x;
    const float4* a4 = (const float4*)(in1 + (size_t)row * D_SZ);
    const float4* b4 = (const float4*)(in2 + (size_t)row * D_SZ);
    float4 a = a4[t], b = b4[t];
    half4 ha = {(_Float16)a.x, (_Float16)a.y, (_Float16)a.z, (_Float16)a.w};
    half4 hb = {(_Float16)b.x, (_Float16)b.y, (_Float16)b.z, (_Float16)b.w};
    ((half4*)(Xh + (size_t)row * D_SZ))[t] = ha;
    ((half4*)(Yh + (size_t)row * D_SZ))[t] = hb;
    float sa = a.x * a.x + a.y * a.y + a.z * a.z + a.w * a.w;
    float sb = b.x * b.x + b.y * b.y + b.z * b.z + b.w * b.w;
    float d0 = a.x - b.x, d1 = a.y - b.y, d2v = a.z - b.z, d3 = a.w - b.w;
    float sd = d0 * d0 + d1 * d1 + d2v * d2v + d3 * d3;
    sa = wave_reduce_add(sa);
    sb = wave_reduce_add(sb);
    sd = wave_reduce_add(sd);
    __shared__ float red[3][4];
    int wave = t >> 6, lane = t & 63;
    if (lane == 0) { red[0][wave] = sa; red[1][wave] = sb; red[2][wave] = sd; }
    __syncthreads();
    if (t == 0) {
        x2[row] = red[0][0] + red[0][1] + red[0][2] + red[0][3];
        y2[row] = red[1][0] + red[1][1] + red[1][2] + red[1][3];
        mth[row] = sqrtf(red[2][0] + red[2][1] + red[2][2] + red[2][3]) + ALPHA;
    }
}

// ---------------------------------------------------------------------------
// gemm_topk: G = Xh @ Yh^T tile (128x128), BK=32 K-loop (R4's proven,
// spill-free, conflict-free structure). Fused epilogue: d2 tile -> LDS fp16
// col-major (Ct[col*132+row], half4 writes), diag pre-clear, then packed
// fp16 selection with wave specialization:
//   waves 0,1: IRR — lane scans a row-PAIR (half2 strided reads; the two
//              packed halves are two different rows), col-halves merged
//              in-wave via shfl_xor(32).
//   waves 2,3: RII — lane owns a full column (half2 contiguous reads; the
//              packed halves are even/odd row sub-streams of the SAME
//              candidate set), merged scalar at the end.
// Candidates: 10 fp16 per (row, tile), layout [row][tile][10].
// ---------------------------------------------------------------------------
__global__ void __launch_bounds__(256, 4) gemm_topk_kernel(
    const _Float16* __restrict__ Xh, const _Float16* __restrict__ Yh,
    const float* __restrict__ x2, const float* __restrict__ y2,
    _Float16* __restrict__ CandI, _Float16* __restrict__ CandR) {
    __shared__ _Float16 smem[16896];   // 33792 B: As+Bs (8192 h) | Ct (16896 h)
    _Float16* As = smem;               // 128 x 32 halves
    _Float16* Bs = smem + 4096;
    int tid = threadIdx.x;
    int wave = tid >> 6, lane = tid & 63;
    int waveR = wave >> 1, waveC = wave & 1;
    int bx = blockIdx.x, by = blockIdx.y;
    int q = lane >> 4, mrow = lane & 15;

    floatx4 acc[4][4] = {};

    // Per-thread staging source (swizzled k-slice), invariant over k0.
    int c0 = tid, c1 = 256 + tid;
    int r0 = c0 >> 2, q0 = (c0 & 3) ^ ((r0 >> 1) & 3);
    int r1 = c1 >> 2, q1 = (c1 & 3) ^ ((r1 >> 1) & 3);
    const _Float16* gA0 = Xh + (size_t)(by * 128 + r0) * D_SZ + q0 * 8;
    const _Float16* gB0 = Yh + (size_t)(bx * 128 + r0) * D_SZ + q0 * 8;
    const _Float16* gA1 = Xh + (size_t)(by * 128 + r1) * D_SZ + q1 * 8;
    const _Float16* gB1 = Yh + (size_t)(bx * 128 + r1) * D_SZ + q1 * 8;
    _Float16* la0 = &As[(wave * 64) * 8];
    _Float16* lb0 = &Bs[(wave * 64) * 8];
    _Float16* la1 = &As[(256 + wave * 64) * 8];
    _Float16* lb1 = &Bs[(256 + wave * 64) * 8];

    int aoff[4], boff[4];
#pragma unroll
    for (int mi = 0; mi < 4; ++mi) {
        int R = waveR * 64 + mi * 16 + mrow;
        aoff[mi] = R * 32 + (q ^ ((R >> 1) & 3)) * 8;
    }
#pragma unroll
    for (int ni = 0; ni < 4; ++ni) {
        int R = waveC * 64 + ni * 16 + mrow;
        boff[ni] = R * 32 + (q ^ ((R >> 1) & 3)) * 8;
    }

    for (int k0 = 0; k0 < D_SZ; k0 += 32) {
        __syncthreads();
        __builtin_amdgcn_global_load_lds((gas_t)(const void*)(gA0 + k0), (las_t)(void*)la0, 16, 0, 0);
        __builtin_amdgcn_global_load_lds((gas_t)(const void*)(gB0 + k0), (las_t)(void*)lb0, 16, 0, 0);
        __builtin_amdgcn_global_load_lds((gas_t)(const void*)(gA1 + k0), (las_t)(void*)la1, 16, 0, 0);
        __builtin_amdgcn_global_load_lds((gas_t)(const void*)(gB1 + k0), (las_t)(void*)lb1, 16, 0, 0);
        __syncthreads();
        half8 af[4], bf[4];
#pragma unroll
        for (int mi = 0; mi < 4; ++mi) af[mi] = *(const half8*)&As[aoff[mi]];
#pragma unroll
        for (int ni = 0; ni < 4; ++ni) bf[ni] = *(const half8*)&Bs[boff[ni]];
#pragma unroll
        for (int mi = 0; mi < 4; ++mi)
#pragma unroll
            for (int ni = 0; ni < 4; ++ni)
                acc[mi][ni] = __builtin_amdgcn_mfma_f32_16x16x32_f16(af[mi], bf[ni], acc[mi][ni], 0, 0, 0);
    }
    __syncthreads();  // staging LDS dead; Ct takes over

    // Phase 1: d2 tile -> LDS fp16 col-major: Ct[col*132 + row].
    // C/D layout: col = lane&15, row = q*4 + reg -> 4 consecutive rows = half4.
    _Float16* Ct = smem;
#pragma unroll
    for (int ni = 0; ni < 4; ++ni) {
        int lc = waveC * 64 + ni * 16 + mrow;
        float y2v = y2[bx * 128 + lc];
#pragma unroll
        for (int mi = 0; mi < 4; ++mi) {
            int lr0 = waveR * 64 + mi * 16 + q * 4;
            int gr0 = by * 128 + lr0;
            floatx4 v = acc[mi][ni];
            half4 hv = {(_Float16)(x2[gr0 + 0] + y2v - 2.0f * v[0]),
                        (_Float16)(x2[gr0 + 1] + y2v - 2.0f * v[1]),
                        (_Float16)(x2[gr0 + 2] + y2v - 2.0f * v[2]),
                        (_Float16)(x2[gr0 + 3] + y2v - 2.0f * v[3])};
            *(half4*)&Ct[lc * CT_STRIDE + lr0] = hv;
        }
    }
    __syncthreads();
    // Diagonal pre-clear (removes all per-element diag masking below).
    if (bx == by && tid < 128) Ct[tid * CT_STRIDE + tid] = (_Float16)SENT_F;
    __syncthreads();

    const half2v sent2 = {(_Float16)SENT_F, (_Float16)SENT_F};

    if (wave < 2) {
        // IRR: lane -> row-pair p (rows 2p, 2p+1), col-half chalf.
        int p = wave * 32 + (lane & 31);     // 0..63
        int chalf = lane >> 5;
        half2v b[10];
#pragma unroll
        for (int i = 0; i < 10; ++i) b[i] = sent2;
#pragma unroll 8
        for (int i = 0; i < 64; ++i) {
            int c = chalf * 64 + i;
            half2v v = *(const half2v*)&Ct[c * CT_STRIDE + 2 * p];
            insert10p(b, v);
        }
        // merge the two col-halves (lanes l <-> l^32)
        half2v t[10];
#pragma unroll
        for (int k = 0; k < 10; ++k)
            t[k] = __builtin_bit_cast(half2v, __shfl_xor(__builtin_bit_cast(int, b[k]), 32));
#pragma unroll
        for (int k = 0; k < 10; ++k) insert10p(b, t[k]);
        if (lane < 32) {
            int grow = by * 128 + 2 * p;
            unsigned int* d0 = (unsigned int*)CandI + ((size_t)grow * 32 + bx) * 5;
            unsigned int* d1 = d0 + 32 * 5;  // row grow+1
#pragma unroll
            for (int k = 0; k < 5; ++k) {
                unsigned int u0 = __builtin_bit_cast(unsigned int, b[2 * k]);
                unsigned int u1 = __builtin_bit_cast(unsigned int, b[2 * k + 1]);
                d0[k] = (u0 & 0xFFFFu) | (u1 << 16);            // low halves = row 2p
                d1[k] = (u0 >> 16) | (u1 & 0xFFFF0000u);        // high halves = row 2p+1
            }
        }
    } else {
        // RII: lane -> full column c; packed halves = even/odd row sub-streams.
        int c = (wave - 2) * 64 + lane;      // 0..127
        half2v b[10];
#pragma unroll
        for (int i = 0; i < 10; ++i) b[i] = sent2;
        const half2v* colp = (const half2v*)&Ct[c * CT_STRIDE];
#pragma unroll 8
        for (int i = 0; i < 64; ++i) insert10p(b, colp[i]);
        float bf[10];
#pragma unroll
        for (int i = 0; i < 10; ++i) bf[i] = BIGF;
#pragma unroll
        for (int k = 0; k < 10; ++k) {
            insert10(bf, (float)b[k][0]);
            insert10(bf, (float)b[k][1]);
        }
        int gcol = bx * 128 + c;
        unsigned int* d = (unsigned int*)CandR + ((size_t)gcol * 32 + by) * 5;
#pragma unroll
        for (int k = 0; k < 5; ++k)
            d[k] = (unsigned int)h16(bf[2 * k]) | ((unsigned int)h16(bf[2 * k + 1]) << 16);
    }
}

// ---------------------------------------------------------------------------
// merge: one wave per logical row r in [0, 8192). Reads 320 fp16 candidates
// (32 tiles x 10), selects global 10 smallest, computes s,z.
// ---------------------------------------------------------------------------
__global__ void __launch_bounds__(256) merge_kernel(
    const _Float16* __restrict__ CandI, const _Float16* __restrict__ CandR,
    const float* __restrict__ mth,
    float* __restrict__ Srow, float* __restrict__ Zrow) {
    int wave = threadIdx.x >> 6, lane = threadIdx.x & 63;
    int r = blockIdx.x * 4 + wave;              // 0..8191
    int row = r & (B_SZ - 1);
    const _Float16* cp = ((r < B_SZ) ? CandI : CandR) + (size_t)row * 320;
    float best[10];
#pragma unroll
    for (int i = 0; i < 10; ++i) best[i] = BIGF;
#pragma unroll
    for (int j = 0; j < 5; ++j) insert10(best, (float)cp[j * 64 + lane]);

    float mrow = mth[row];
    float s = 0.f, z = 0.f;
#pragma unroll
    for (int round = 0; round < 10; ++round) {
        float v0 = best[0];
        float g = v0;
#pragma unroll
        for (int off = 32; off; off >>= 1) g = fminf(g, __shfl_xor(g, off));
        unsigned long long ball = __ballot(v0 == g);
        int leader = __ffsll(ball) - 1;
        if (lane == leader) {
#pragma unroll
            for (int p = 0; p < 9; ++p) best[p] = best[p + 1];
            best[9] = BIGF;
        }
        float d = sqrtf(fmaxf(g, 0.f));
        float c = fmaxf(mrow - d, 0.f);
        s += c;
        z += (c == 0.f) ? 1.f : 0.f;
    }
    if (lane == 0) { Srow[r] = s; Zrow[r] = z; }
}

// ---------------------------------------------------------------------------
// finalize: reduce per-row partials -> [loss_irr, loss_rii, bad_irr, bad_rii]
// ---------------------------------------------------------------------------
__global__ void __launch_bounds__(256) finalize_kernel(
    const float* __restrict__ Srow, const float* __restrict__ Zrow,
    float* __restrict__ out) {
    __shared__ float red[256][4];
    int t = threadIdx.x;
    float s0 = 0, s1 = 0, z0 = 0, z1 = 0;
#pragma unroll
    for (int k = 0; k < 8; ++k) {
        int i = k * 256 + t;
        float4 sv = ((const float4*)Srow)[i];
        float4 zv = ((const float4*)Zrow)[i];
        float ss = sv.x + sv.y + sv.z + sv.w;
        float zz = zv.x + zv.y + zv.z + zv.w;
        if (i < 1024) { s0 += ss; z0 += zz; } else { s1 += ss; z1 += zz; }
    }
    red[t][0] = s0; red[t][1] = s1; red[t][2] = z0; red[t][3] = z1;
    __syncthreads();
    for (int off = 128; off > 0; off >>= 1) {
        if (t < off) {
#pragma unroll
            for (int j = 0; j < 4; ++j) red[t][j] += red[t + off][j];
        }
        __syncthreads();
    }
    if (t == 0) {
        const float inv = 1.0f / (float)(B_SZ * 10);
        out[0] = red[0][0] * inv;  // loss_irr
        out[1] = red[0][1] * inv;  // loss_rii
        out[2] = red[0][2] * inv;  // bad_irr
        out[3] = red[0][3] * inv;  // bad_rii
    }
}

// ---------------------------------------------------------------------------
extern "C" void kernel_launch(void* const* d_in, const int* in_sizes, int n_in,
                              void* d_out, int out_size, void* d_ws, size_t ws_size,
                              hipStream_t stream) {
    const float* in1 = (const float*)d_in[0];
    const float* in2 = (const float*)d_in[1];
    float* out = (float*)d_out;

    char* ws = (char*)d_ws;
    const size_t MB = 1024 * 1024;
    _Float16* Xh = (_Float16*)(ws);                  // 8 MiB
    _Float16* Yh = (_Float16*)(ws + 8 * MB);         // 8 MiB
    _Float16* CandI = (_Float16*)(ws + 16 * MB);     // 4096*32*10*2B = 2.62 MB
    _Float16* CandR = (_Float16*)(ws + 19 * MB);     // 2.62 MB
    float* x2   = (float*)(ws + 22 * MB);
    float* y2   = x2 + B_SZ;
    float* mth  = y2 + B_SZ;
    float* Srow = mth + B_SZ;                        // 2*B rows (irr then rii)
    float* Zrow = Srow + 2 * B_SZ;
    const size_t needed = 22 * MB + (size_t)(3 * B_SZ + 4 * B_SZ) * sizeof(float);
    if (ws_size < needed) return;

    hipLaunchKernelGGL(prep_kernel, dim3(B_SZ), dim3(256), 0, stream,
                       in1, in2, Xh, Yh, x2, y2, mth);
    hipLaunchKernelGGL(gemm_topk_kernel, dim3(32, 32), dim3(256), 0, stream,
                       Xh, Yh, x2, y2, CandI, CandR);
    hipLaunchKernelGGL(merge_kernel, dim3(2048), dim3(256), 0, stream,
                       CandI, CandR, mth, Srow, Zrow);
    hipLaunchKernelGGL(finalize_kernel, dim3(1), dim3(256), 0, stream,
                       Srow, Zrow, out);
}